// Round 1
// baseline (197.509 us; speedup 1.0000x reference)
//
#include <hip/hip_runtime.h>
#include <hip/hip_bf16.h>

typedef __attribute__((ext_vector_type(8))) __bf16 bf16x8;
typedef __attribute__((ext_vector_type(4))) float f32x4;
typedef __attribute__((ext_vector_type(4))) unsigned short u16x4;
typedef unsigned short u16;

typedef __attribute__((address_space(1))) void gvoid;
typedef __attribute__((address_space(3))) void lvoid;

#define B_DIM 8192
#define H_DIM 512

__device__ __forceinline__ u16x4 cvt4(f32x4 v) {
    u16x4 r;
    r.x = __builtin_bit_cast(u16, __float2bfloat16(v.x));
    r.y = __builtin_bit_cast(u16, __float2bfloat16(v.y));
    r.z = __builtin_bit_cast(u16, __float2bfloat16(v.z));
    r.w = __builtin_bit_cast(u16, __float2bfloat16(v.w));
    return r;
}

// ---------------- all_zero flag ----------------
__global__ void k_flag(const int* __restrict__ pd, int* __restrict__ flag) {
    __shared__ int s;
    if (threadIdx.x == 0) s = 0;
    __syncthreads();
    int any = 0;
    for (int i = threadIdx.x; i < B_DIM; i += 1024) any |= pd[i];
    if (any) atomicOr(&s, 1);
    __syncthreads();
    if (threadIdx.x == 0) flag[0] = (s == 0) ? 1 : 0;
}

// ---------------- per-row prep: f, j, next_depth, blend coeffs ----------------
// coeffs[row] = {eq*fj, eq*nn, eq*fn, lt}
__global__ void k_prep(const float* __restrict__ prev_b, const int* __restrict__ prev_depth,
                       const float* __restrict__ w_f, const int* __restrict__ flag,
                       float* __restrict__ coeffs, float* __restrict__ outD,
                       float* __restrict__ outF, float* __restrict__ outJ) {
    int row = blockIdx.x * 4 + (threadIdx.x >> 6);
    int lane = threadIdx.x & 63;
    if (row >= B_DIM) return;
    int depth = prev_depth[row];
    const float* bt = prev_b + (size_t)row * 2 * H_DIM + (size_t)depth * H_DIM;
    f32x4 v0 = *(const f32x4*)(bt + lane * 8);
    f32x4 v1 = *(const f32x4*)(bt + lane * 8 + 4);
    f32x4 w0 = *(const f32x4*)(w_f + lane * 8);
    f32x4 w1 = *(const f32x4*)(w_f + lane * 8 + 4);
    float dot = v0.x*w0.x + v0.y*w0.y + v0.z*w0.z + v0.w*w0.w
              + v1.x*w1.x + v1.y*w1.y + v1.z*w1.z + v1.w*w1.w;
    for (int off = 32; off > 0; off >>= 1) dot += __shfl_xor(dot, off, 64);
    if (lane == 0) {
        int az = flag[0];
        float sg = 1.0f / (1.0f + expf(-dot));
        float fr = rintf(sg);               // round-half-even, matches jnp.round
        float f = az ? 1.0f : fr;
        float j = az ? 0.0f : fr;
        int nd = depth + (int)(f - j);
        float eq = (nd == 1) ? 1.0f : 0.0f;
        float lt = (nd < 1) ? 1.0f : 0.0f;
        float fj = f * j;
        float nn = (1.0f - f) * (1.0f - j);
        float fn = f * (1.0f - j);
        f32x4 c; c.x = eq * fj; c.y = eq * nn; c.z = eq * fn; c.w = lt;
        *(f32x4*)(coeffs + (size_t)row * 4) = c;
        outD[row] = (float)nd;
        outF[row] = f;
        outJ[row] = j;
    }
}

// ---------------- convert activations to bf16 + zero-fill depth-0 output slabs ----------------
__global__ void k_conv_in(const float* __restrict__ X, const float* __restrict__ prev_a,
                          const float* __restrict__ prev_b,
                          u16* __restrict__ Xb, u16* __restrict__ pab,
                          u16* __restrict__ pb0b, u16* __restrict__ pb1b,
                          float* __restrict__ outA, float* __restrict__ outB) {
    int tid = blockIdx.x * 256 + threadIdx.x;
    if (tid >= B_DIM * 128) return;
    int b = tid >> 7;
    int i = (tid & 127) * 4;
    f32x4 x  = *(const f32x4*)(X + (size_t)b * 512 + i);
    f32x4 pa = *(const f32x4*)(prev_a + (size_t)b * 1024 + 512 + i);
    f32x4 p0 = *(const f32x4*)(prev_b + (size_t)b * 1024 + i);
    f32x4 p1 = *(const f32x4*)(prev_b + (size_t)b * 1024 + 512 + i);
    *(u16x4*)(Xb   + (size_t)b * 512 + i) = cvt4(x);
    *(u16x4*)(pab  + (size_t)b * 512 + i) = cvt4(pa);
    *(u16x4*)(pb0b + (size_t)b * 512 + i) = cvt4(p0);
    *(u16x4*)(pb1b + (size_t)b * 512 + i) = cvt4(p1);
    f32x4 z; z.x = 0.f; z.y = 0.f; z.z = 0.f; z.w = 0.f;
    *(f32x4*)(outA + (size_t)b * 1024 + i) = z;   // next_a[:,0,:]
    *(f32x4*)(outB + (size_t)b * 1024 + i) = z;   // next_b[:,0,:]
}

// ---------------- convert all 5 weight matrices to bf16 ----------------
__global__ void k_conv_w(const float* __restrict__ wa00, const float* __restrict__ wa10,
                         const float* __restrict__ wb00, const float* __restrict__ wb11,
                         const float* __restrict__ wb10,
                         u16* __restrict__ oa00, u16* __restrict__ oa10,
                         u16* __restrict__ ob00, u16* __restrict__ ob11,
                         u16* __restrict__ ob10) {
    int t = blockIdx.x * 256 + threadIdx.x;
    const int S  = 512 * 1024 / 4;   // 131072
    const int SB = 512 * 1536 / 4;   // 196608
    const float* src; u16* dst; int off;
    if      (t < S)            { src = wa00; dst = oa00; off = t; }
    else if (t < 2 * S)        { src = wa10; dst = oa10; off = t - S; }
    else if (t < 2 * S + SB)   { src = wb00; dst = ob00; off = t - 2 * S; }
    else if (t < 3 * S + SB)   { src = wb11; dst = ob11; off = t - 2 * S - SB; }
    else if (t < 4 * S + SB)   { src = wb10; dst = ob10; off = t - 3 * S - SB; }
    else return;
    f32x4 v = *(const f32x4*)(src + (size_t)off * 4);
    *(u16x4*)(dst + (size_t)off * 4) = cvt4(v);
}

// ---------------- bf16 GEMM: out[M=8192][N=512] = concat(srcs) @ W^T ----------------
// Each src is [8192][512] bf16 row-major; W is [512][NSRC*512] bf16 row-major.
// 128x128 tile, BK=64, 256 threads (4 waves, each 64x64), 16x16x32 bf16 MFMA.
template<int NSRC>
__global__ __launch_bounds__(256, 2) void k_gemm(const u16* __restrict__ s0,
                                                 const u16* __restrict__ s1,
                                                 const u16* __restrict__ s2,
                                                 const u16* __restrict__ w,
                                                 float* __restrict__ out) {
    __shared__ u16 lsA[128 * 64];
    __shared__ u16 lsB[128 * 64];
    const int Kw = NSRC * 512;
    const int t = threadIdx.x;
    const int bid = blockIdx.x;
    const int m0 = (bid >> 2) << 7;
    const int n0 = (bid & 3) << 7;
    const int lane = t & 63;
    const int wv = t >> 6;
    const int wr = (wv >> 1) << 6;
    const int wc = (wv & 1) << 6;
    const int fr = lane & 15;
    const int fq = lane >> 4;

    f32x4 acc[4][4] = {};

    const u16* srcs[3] = {s0, s1, s2};
#pragma unroll
    for (int chunk = 0; chunk < NSRC; ++chunk) {
        const u16* sp = srcs[chunk];
        for (int kq = 0; kq < 8; ++kq) {
            int cb = kq << 6;
#pragma unroll
            for (int it = 0; it < 4; ++it) {
                int e = it * 2048 + t * 8;
                int r = e >> 6, c = e & 63;
                const u16* ga = sp + (size_t)(m0 + r) * 512 + cb + c;
                __builtin_amdgcn_global_load_lds((gvoid*)ga, (lvoid*)&lsA[e], 16, 0, 0);
                const u16* gb = w + (size_t)(n0 + r) * Kw + (chunk << 9) + cb + c;
                __builtin_amdgcn_global_load_lds((gvoid*)gb, (lvoid*)&lsB[e], 16, 0, 0);
            }
            __syncthreads();
#pragma unroll
            for (int kk = 0; kk < 2; ++kk) {
                bf16x8 af[4], bf[4];
#pragma unroll
                for (int mi = 0; mi < 4; ++mi)
                    af[mi] = *(const bf16x8*)&lsA[(wr + mi * 16 + fr) * 64 + kk * 32 + fq * 8];
#pragma unroll
                for (int ni = 0; ni < 4; ++ni)
                    bf[ni] = *(const bf16x8*)&lsB[(wc + ni * 16 + fr) * 64 + kk * 32 + fq * 8];
#pragma unroll
                for (int mi = 0; mi < 4; ++mi)
#pragma unroll
                    for (int ni = 0; ni < 4; ++ni)
                        acc[mi][ni] = __builtin_amdgcn_mfma_f32_16x16x32_bf16(af[mi], bf[ni], acc[mi][ni], 0, 0, 0);
            }
            __syncthreads();
        }
    }
#pragma unroll
    for (int mi = 0; mi < 4; ++mi)
#pragma unroll
        for (int ni = 0; ni < 4; ++ni) {
            int col = n0 + wc + ni * 16 + fr;
#pragma unroll
            for (int jj = 0; jj < 4; ++jj) {
                int row = m0 + wr + mi * 16 + fq * 4 + jj;
                out[(size_t)row * H_DIM + col] = acc[mi][ni][jj];
            }
        }
}

// ---------------- epilogue A: next_a1 = (e_fj+lt)*pa + e_nn*ga00 + e_fn*ga10 ----------------
__global__ void k_epiA(const float* __restrict__ g00, const float* __restrict__ g10,
                       const float* __restrict__ prev_a, const float* __restrict__ coeffs,
                       float* __restrict__ outA, u16* __restrict__ na1b) {
    int tid = blockIdx.x * 256 + threadIdx.x;
    if (tid >= B_DIM * 128) return;
    int b = tid >> 7;
    int i = (tid & 127) * 4;
    f32x4 c = *(const f32x4*)(coeffs + (size_t)b * 4);
    f32x4 a00 = *(const f32x4*)(g00 + (size_t)b * 512 + i);
    f32x4 a10 = *(const f32x4*)(g10 + (size_t)b * 512 + i);
    f32x4 pa  = *(const f32x4*)(prev_a + (size_t)b * 1024 + 512 + i);
    float cpa = c.x + c.w;
    f32x4 r;
    r.x = cpa * pa.x + c.y * a00.x + c.z * a10.x;
    r.y = cpa * pa.y + c.y * a00.y + c.z * a10.y;
    r.z = cpa * pa.z + c.y * a00.z + c.z * a10.z;
    r.w = cpa * pa.w + c.y * a00.w + c.z * a10.w;
    *(f32x4*)(outA + (size_t)b * 1024 + 512 + i) = r;   // next_a[:,1,:]
    *(u16x4*)(na1b + (size_t)b * 512 + i) = cvt4(r);
}

// ---------------- epilogue B: next_b1 = e_fj*gb11 + e_nn*gb00 + e_fn*gb10 + lt*pb1 ----------------
__global__ void k_epiB(const float* __restrict__ g00, const float* __restrict__ g10,
                       const float* __restrict__ g11, const float* __restrict__ prev_b,
                       const float* __restrict__ coeffs, float* __restrict__ outB) {
    int tid = blockIdx.x * 256 + threadIdx.x;
    if (tid >= B_DIM * 128) return;
    int b = tid >> 7;
    int i = (tid & 127) * 4;
    f32x4 c = *(const f32x4*)(coeffs + (size_t)b * 4);
    f32x4 b00 = *(const f32x4*)(g00 + (size_t)b * 512 + i);
    f32x4 b10 = *(const f32x4*)(g10 + (size_t)b * 512 + i);
    f32x4 b11 = *(const f32x4*)(g11 + (size_t)b * 512 + i);
    f32x4 p1  = *(const f32x4*)(prev_b + (size_t)b * 1024 + 512 + i);
    f32x4 r;
    r.x = c.x * b11.x + c.y * b00.x + c.z * b10.x + c.w * p1.x;
    r.y = c.x * b11.y + c.y * b00.y + c.z * b10.y + c.w * p1.y;
    r.z = c.x * b11.z + c.y * b00.z + c.z * b10.z + c.w * p1.z;
    r.w = c.x * b11.w + c.y * b00.w + c.z * b10.w + c.w * p1.w;
    *(f32x4*)(outB + (size_t)b * 1024 + 512 + i) = r;   // next_b[:,1,:]
}

extern "C" void kernel_launch(void* const* d_in, const int* in_sizes, int n_in,
                              void* d_out, int out_size, void* d_ws, size_t ws_size,
                              hipStream_t stream) {
    const float* X          = (const float*)d_in[0];
    const float* prev_a     = (const float*)d_in[1];
    const float* prev_b     = (const float*)d_in[2];
    const int*   prev_depth = (const int*)d_in[3];
    const float* w_f        = (const float*)d_in[4];
    const float* w_a00      = (const float*)d_in[5];
    const float* w_a10      = (const float*)d_in[6];
    const float* w_b00      = (const float*)d_in[7];
    const float* w_b11      = (const float*)d_in[8];
    const float* w_b10      = (const float*)d_in[9];

    float* out  = (float*)d_out;
    float* outA = out;                       // next_a: B x 2 x H
    float* outB = out + 8388608;             // next_b
    float* outD = out + 16777216;            // next_depth (as float)
    float* outF = outD + 8192;               // f
    float* outJ = outF + 8192;               // j

    char* ws = (char*)d_ws;
    size_t off = 0;
    auto alloc = [&](size_t bytes) -> char* {
        char* p = ws + off;
        off += (bytes + 255) & ~(size_t)255;
        return p;
    };
    u16* Xb    = (u16*)alloc((size_t)B_DIM * 512 * 2);
    u16* pab   = (u16*)alloc((size_t)B_DIM * 512 * 2);
    u16* pb0b  = (u16*)alloc((size_t)B_DIM * 512 * 2);
    u16* pb1b  = (u16*)alloc((size_t)B_DIM * 512 * 2);
    u16* na1b  = (u16*)alloc((size_t)B_DIM * 512 * 2);
    u16* wa00b = (u16*)alloc((size_t)512 * 1024 * 2);
    u16* wa10b = (u16*)alloc((size_t)512 * 1024 * 2);
    u16* wb00b = (u16*)alloc((size_t)512 * 1536 * 2);
    u16* wb11b = (u16*)alloc((size_t)512 * 1024 * 2);
    u16* wb10b = (u16*)alloc((size_t)512 * 1024 * 2);
    float* buf0 = (float*)alloc((size_t)B_DIM * 512 * 4);
    float* buf1 = (float*)alloc((size_t)B_DIM * 512 * 4);
    float* buf2 = (float*)alloc((size_t)B_DIM * 512 * 4);
    float* coeffs = (float*)alloc((size_t)B_DIM * 16);
    int* flag = (int*)alloc(256);
    if (off > ws_size) return;  // workspace too small — fail loudly

    k_flag<<<1, 1024, 0, stream>>>(prev_depth, flag);
    k_prep<<<2048, 256, 0, stream>>>(prev_b, prev_depth, w_f, flag, coeffs, outD, outF, outJ);
    k_conv_in<<<4096, 256, 0, stream>>>(X, prev_a, prev_b, Xb, pab, pb0b, pb1b, outA, outB);
    k_conv_w<<<2816, 256, 0, stream>>>(w_a00, w_a10, w_b00, w_b11, w_b10,
                                       wa00b, wa10b, wb00b, wb11b, wb10b);
    // phase 1: a00 = [X|pa] @ w_a00^T ; a10 = [X|pb0] @ w_a10^T
    k_gemm<2><<<256, 256, 0, stream>>>(Xb, pab, nullptr, wa00b, buf0);
    k_gemm<2><<<256, 256, 0, stream>>>(Xb, pb0b, nullptr, wa10b, buf1);
    k_epiA<<<4096, 256, 0, stream>>>(buf0, buf1, prev_a, coeffs, outA, na1b);
    // phase 2: b00 = [X|pa|na1] @ w_b00^T ; b10 = [X|na1] @ w_b10^T ; b11 = [X|pb1] @ w_b11^T
    k_gemm<3><<<256, 256, 0, stream>>>(Xb, pab, na1b, wb00b, buf0);
    k_gemm<2><<<256, 256, 0, stream>>>(Xb, na1b, nullptr, wb10b, buf1);
    k_gemm<2><<<256, 256, 0, stream>>>(Xb, pb1b, nullptr, wb11b, buf2);
    k_epiB<<<4096, 256, 0, stream>>>(buf0, buf1, buf2, prev_b, coeffs, outB);
}

// Round 2
// 122.987 us; speedup vs baseline: 1.6059x; 1.6059x over previous
//
#include <hip/hip_runtime.h>
#include <hip/hip_bf16.h>

typedef __attribute__((ext_vector_type(8))) __bf16 bf16x8;
typedef __attribute__((ext_vector_type(4))) float f32x4;
typedef __attribute__((ext_vector_type(4))) unsigned short u16x4;
typedef unsigned short u16;

typedef __attribute__((address_space(1))) void gvoid;
typedef __attribute__((address_space(3))) void lvoid;

#define B_DIM 8192
#define H_DIM 512

__device__ __forceinline__ u16x4 cvt4(f32x4 v) {
    u16x4 r;
    r.x = __builtin_bit_cast(u16, __float2bfloat16(v.x));
    r.y = __builtin_bit_cast(u16, __float2bfloat16(v.y));
    r.z = __builtin_bit_cast(u16, __float2bfloat16(v.z));
    r.w = __builtin_bit_cast(u16, __float2bfloat16(v.w));
    return r;
}

// stage an R x 64 bf16 tile (row-major, leading dim ldg) into LDS [R][64]
template<int R>
__device__ __forceinline__ void stage_tile(const u16* g, int ldg, u16* ls, int t) {
#pragma unroll
    for (int it = 0; it < R / 32; ++it) {
        int e = it * 2048 + t * 8;
        int r = e >> 6, c = e & 63;
        __builtin_amdgcn_global_load_lds((gvoid*)(g + (size_t)r * ldg + c),
                                         (lvoid*)&ls[e], 16, 0, 0);
    }
}

// ---------------- all_zero flag ----------------
__global__ void k_flag(const int* __restrict__ pd, int* __restrict__ flag) {
    __shared__ int s;
    if (threadIdx.x == 0) s = 0;
    __syncthreads();
    int any = 0;
    for (int i = threadIdx.x; i < B_DIM; i += 1024) any |= pd[i];
    if (any) atomicOr(&s, 1);
    __syncthreads();
    if (threadIdx.x == 0) flag[0] = (s == 0) ? 1 : 0;
}

// ---------------- fused prep: f/j/depth/coeffs + bf16 conversion + zero slabs ----------------
// one wave per row; grid 2048 x 256
__global__ void k_prep2(const float* __restrict__ X, const float* __restrict__ prev_a,
                        const float* __restrict__ prev_b, const int* __restrict__ prev_depth,
                        const float* __restrict__ w_f, const int* __restrict__ flag,
                        u16* __restrict__ Xb, u16* __restrict__ pab,
                        u16* __restrict__ pb0b, u16* __restrict__ pb1b,
                        float* __restrict__ coeffs, float* __restrict__ outA,
                        float* __restrict__ outB, float* __restrict__ outD,
                        float* __restrict__ outF, float* __restrict__ outJ) {
    int wv = threadIdx.x >> 6, l = threadIdx.x & 63;
    int row = blockIdx.x * 4 + wv;
    size_t r512 = (size_t)row * 512, r1024 = (size_t)row * 1024;
    int i = l * 8;
    f32x4 x0  = *(const f32x4*)(X + r512 + i);
    f32x4 x1  = *(const f32x4*)(X + r512 + i + 4);
    f32x4 pa0 = *(const f32x4*)(prev_a + r1024 + 512 + i);
    f32x4 pa1 = *(const f32x4*)(prev_a + r1024 + 512 + i + 4);
    f32x4 q00 = *(const f32x4*)(prev_b + r1024 + i);
    f32x4 q01 = *(const f32x4*)(prev_b + r1024 + i + 4);
    f32x4 q10 = *(const f32x4*)(prev_b + r1024 + 512 + i);
    f32x4 q11 = *(const f32x4*)(prev_b + r1024 + 512 + i + 4);
    f32x4 w0  = *(const f32x4*)(w_f + i);
    f32x4 w1  = *(const f32x4*)(w_f + i + 4);
    int depth = prev_depth[row];
    f32x4 b0 = depth ? q10 : q00;
    f32x4 b1 = depth ? q11 : q01;
    float dot = b0.x*w0.x + b0.y*w0.y + b0.z*w0.z + b0.w*w0.w
              + b1.x*w1.x + b1.y*w1.y + b1.z*w1.z + b1.w*w1.w;
    for (int off = 32; off > 0; off >>= 1) dot += __shfl_xor(dot, off, 64);

    *(u16x4*)(Xb   + r512 + i)     = cvt4(x0);
    *(u16x4*)(Xb   + r512 + i + 4) = cvt4(x1);
    *(u16x4*)(pab  + r512 + i)     = cvt4(pa0);
    *(u16x4*)(pab  + r512 + i + 4) = cvt4(pa1);
    *(u16x4*)(pb0b + r512 + i)     = cvt4(q00);
    *(u16x4*)(pb0b + r512 + i + 4) = cvt4(q01);
    *(u16x4*)(pb1b + r512 + i)     = cvt4(q10);
    *(u16x4*)(pb1b + r512 + i + 4) = cvt4(q11);
    f32x4 z; z.x = 0.f; z.y = 0.f; z.z = 0.f; z.w = 0.f;
    *(f32x4*)(outA + r1024 + i)     = z;
    *(f32x4*)(outA + r1024 + i + 4) = z;
    *(f32x4*)(outB + r1024 + i)     = z;
    *(f32x4*)(outB + r1024 + i + 4) = z;

    if (l == 0) {
        int az = flag[0];
        float sg = 1.0f / (1.0f + expf(-dot));
        float fr = rintf(sg);
        float f = az ? 1.0f : fr;
        float j = az ? 0.0f : fr;
        int nd = depth + (int)(f - j);
        float eq = (nd == 1) ? 1.0f : 0.0f;
        float lt = (nd < 1) ? 1.0f : 0.0f;
        f32x4 c; c.x = eq * (f * j); c.y = eq * (1.0f - f) * (1.0f - j);
        c.z = eq * f * (1.0f - j); c.w = lt;
        *(f32x4*)(coeffs + (size_t)row * 4) = c;
        outD[row] = (float)nd;
        outF[row] = f;
        outJ[row] = j;
    }
}

// ---------------- convert all 5 weight matrices to bf16 ----------------
__global__ void k_conv_w(const float* __restrict__ wa00, const float* __restrict__ wa10,
                         const float* __restrict__ wb00, const float* __restrict__ wb11,
                         const float* __restrict__ wb10,
                         u16* __restrict__ oa00, u16* __restrict__ oa10,
                         u16* __restrict__ ob00, u16* __restrict__ ob11,
                         u16* __restrict__ ob10) {
    int t = blockIdx.x * 256 + threadIdx.x;
    const int S  = 512 * 1024 / 4;
    const int SB = 512 * 1536 / 4;
    const float* src; u16* dst; int off;
    if      (t < S)            { src = wa00; dst = oa00; off = t; }
    else if (t < 2 * S)        { src = wa10; dst = oa10; off = t - S; }
    else if (t < 2 * S + SB)   { src = wb00; dst = ob00; off = t - 2 * S; }
    else if (t < 3 * S + SB)   { src = wb11; dst = ob11; off = t - 2 * S - SB; }
    else if (t < 4 * S + SB)   { src = wb10; dst = ob10; off = t - 3 * S - SB; }
    else return;
    f32x4 v = *(const f32x4*)(src + (size_t)off * 4);
    *(u16x4*)(dst + (size_t)off * 4) = cvt4(v);
}

// ---------------- phase-1 fused GEMM: a00 & a10 + epilogue A ----------------
// grid 512 = 128 M-tiles (64 rows) x 4 N-tiles (128 cols); 256 threads; 2 blocks/CU
__global__ __launch_bounds__(256, 2) void k_gemmA(
    const u16* __restrict__ Xb, const u16* __restrict__ pab, const u16* __restrict__ pb0b,
    const u16* __restrict__ w0, const u16* __restrict__ w1,
    const float* __restrict__ prev_a, const float* __restrict__ coeffs,
    float* __restrict__ outA, u16* __restrict__ na1b)
{
    __shared__ u16 lsA0[64 * 64];
    __shared__ u16 lsA1[64 * 64];
    __shared__ u16 lsB0[128 * 64];
    __shared__ u16 lsB1[128 * 64];
    const int t = threadIdx.x;
    const int m0 = ((int)blockIdx.x >> 2) * 64;
    const int n0 = ((int)blockIdx.x & 3) * 128;
    const int lane = t & 63, wv = t >> 6;
    const int wr = (wv >> 1) * 32, wc = (wv & 1) * 64;
    const int fr = lane & 15, fq = lane >> 4;
    const int lofs = fq * 8;

    f32x4 acc0[2][4] = {}, acc1[2][4] = {};

    // half 1: k in [0,512), A = X for both outputs
    for (int kq = 0; kq < 8; ++kq) {
        int cb = kq * 64;
        stage_tile<64>(Xb + (size_t)m0 * 512 + cb, 512, lsA0, t);
        stage_tile<128>(w0 + (size_t)n0 * 1024 + cb, 1024, lsB0, t);
        stage_tile<128>(w1 + (size_t)n0 * 1024 + cb, 1024, lsB1, t);
        __syncthreads();
#pragma unroll
        for (int kk = 0; kk < 2; ++kk) {
            bf16x8 a[2], b0[4], b1[4];
#pragma unroll
            for (int mi = 0; mi < 2; ++mi)
                a[mi] = *(const bf16x8*)&lsA0[(wr + mi * 16 + fr) * 64 + kk * 32 + lofs];
#pragma unroll
            for (int ni = 0; ni < 4; ++ni) {
                b0[ni] = *(const bf16x8*)&lsB0[(wc + ni * 16 + fr) * 64 + kk * 32 + lofs];
                b1[ni] = *(const bf16x8*)&lsB1[(wc + ni * 16 + fr) * 64 + kk * 32 + lofs];
            }
#pragma unroll
            for (int mi = 0; mi < 2; ++mi)
#pragma unroll
                for (int ni = 0; ni < 4; ++ni) {
                    acc0[mi][ni] = __builtin_amdgcn_mfma_f32_16x16x32_bf16(a[mi], b0[ni], acc0[mi][ni], 0, 0, 0);
                    acc1[mi][ni] = __builtin_amdgcn_mfma_f32_16x16x32_bf16(a[mi], b1[ni], acc1[mi][ni], 0, 0, 0);
                }
        }
        __syncthreads();
    }
    // half 2: k in [512,1024), A0 = pa (acc0), A1 = pb0 (acc1)
    for (int kq = 0; kq < 8; ++kq) {
        int cb = kq * 64;
        stage_tile<64>(pab + (size_t)m0 * 512 + cb, 512, lsA0, t);
        stage_tile<64>(pb0b + (size_t)m0 * 512 + cb, 512, lsA1, t);
        stage_tile<128>(w0 + (size_t)n0 * 1024 + 512 + cb, 1024, lsB0, t);
        stage_tile<128>(w1 + (size_t)n0 * 1024 + 512 + cb, 1024, lsB1, t);
        __syncthreads();
#pragma unroll
        for (int kk = 0; kk < 2; ++kk) {
            bf16x8 a0[2], a1[2], b0[4], b1[4];
#pragma unroll
            for (int mi = 0; mi < 2; ++mi) {
                a0[mi] = *(const bf16x8*)&lsA0[(wr + mi * 16 + fr) * 64 + kk * 32 + lofs];
                a1[mi] = *(const bf16x8*)&lsA1[(wr + mi * 16 + fr) * 64 + kk * 32 + lofs];
            }
#pragma unroll
            for (int ni = 0; ni < 4; ++ni) {
                b0[ni] = *(const bf16x8*)&lsB0[(wc + ni * 16 + fr) * 64 + kk * 32 + lofs];
                b1[ni] = *(const bf16x8*)&lsB1[(wc + ni * 16 + fr) * 64 + kk * 32 + lofs];
            }
#pragma unroll
            for (int mi = 0; mi < 2; ++mi)
#pragma unroll
                for (int ni = 0; ni < 4; ++ni) {
                    acc0[mi][ni] = __builtin_amdgcn_mfma_f32_16x16x32_bf16(a0[mi], b0[ni], acc0[mi][ni], 0, 0, 0);
                    acc1[mi][ni] = __builtin_amdgcn_mfma_f32_16x16x32_bf16(a1[mi], b1[ni], acc1[mi][ni], 0, 0, 0);
                }
        }
        __syncthreads();
    }
    // fused epilogue A
#pragma unroll
    for (int mi = 0; mi < 2; ++mi)
#pragma unroll
        for (int jj = 0; jj < 4; ++jj) {
            int row = m0 + wr + mi * 16 + fq * 4 + jj;
            f32x4 c = *(const f32x4*)(coeffs + (size_t)row * 4);
            float cpa = c.x + c.w;
#pragma unroll
            for (int ni = 0; ni < 4; ++ni) {
                int col = n0 + wc + ni * 16 + fr;
                float pa = prev_a[(size_t)row * 1024 + 512 + col];
                float v = cpa * pa + c.y * acc0[mi][ni][jj] + c.z * acc1[mi][ni][jj];
                outA[(size_t)row * 1024 + 512 + col] = v;
                na1b[(size_t)row * 512 + col] = __builtin_bit_cast(u16, __float2bfloat16(v));
            }
        }
}

// ---------------- phase-2 fused GEMM: b00, b10, b11 + epilogue B ----------------
__global__ __launch_bounds__(256, 2) void k_gemmB(
    const u16* __restrict__ Xb, const u16* __restrict__ pab,
    const u16* __restrict__ na1b, const u16* __restrict__ pb1b,
    const u16* __restrict__ w00, const u16* __restrict__ w10, const u16* __restrict__ w11,
    const float* __restrict__ prev_b, const float* __restrict__ coeffs,
    float* __restrict__ outB)
{
    __shared__ u16 lsA0[64 * 64];
    __shared__ u16 lsA1[64 * 64];
    __shared__ u16 lsA2[64 * 64];
    __shared__ u16 lsB0[128 * 64];
    __shared__ u16 lsB1[128 * 64];
    __shared__ u16 lsB2[128 * 64];
    const int t = threadIdx.x;
    const int m0 = ((int)blockIdx.x >> 2) * 64;
    const int n0 = ((int)blockIdx.x & 3) * 128;
    const int lane = t & 63, wv = t >> 6;
    const int wr = (wv >> 1) * 32, wc = (wv & 1) * 64;
    const int fr = lane & 15, fq = lane >> 4;
    const int lofs = fq * 8;

    f32x4 acc00[2][4] = {}, acc10[2][4] = {}, acc11[2][4] = {};

    // half 1: k in [0,512), A = X for all three
    for (int kq = 0; kq < 8; ++kq) {
        int cb = kq * 64;
        stage_tile<64>(Xb + (size_t)m0 * 512 + cb, 512, lsA0, t);
        stage_tile<128>(w00 + (size_t)n0 * 1536 + cb, 1536, lsB0, t);
        stage_tile<128>(w10 + (size_t)n0 * 1024 + cb, 1024, lsB1, t);
        stage_tile<128>(w11 + (size_t)n0 * 1024 + cb, 1024, lsB2, t);
        __syncthreads();
#pragma unroll
        for (int kk = 0; kk < 2; ++kk) {
            bf16x8 a[2], b0[4], b1[4], b2[4];
#pragma unroll
            for (int mi = 0; mi < 2; ++mi)
                a[mi] = *(const bf16x8*)&lsA0[(wr + mi * 16 + fr) * 64 + kk * 32 + lofs];
#pragma unroll
            for (int ni = 0; ni < 4; ++ni) {
                b0[ni] = *(const bf16x8*)&lsB0[(wc + ni * 16 + fr) * 64 + kk * 32 + lofs];
                b1[ni] = *(const bf16x8*)&lsB1[(wc + ni * 16 + fr) * 64 + kk * 32 + lofs];
                b2[ni] = *(const bf16x8*)&lsB2[(wc + ni * 16 + fr) * 64 + kk * 32 + lofs];
            }
#pragma unroll
            for (int mi = 0; mi < 2; ++mi)
#pragma unroll
                for (int ni = 0; ni < 4; ++ni) {
                    acc00[mi][ni] = __builtin_amdgcn_mfma_f32_16x16x32_bf16(a[mi], b0[ni], acc00[mi][ni], 0, 0, 0);
                    acc10[mi][ni] = __builtin_amdgcn_mfma_f32_16x16x32_bf16(a[mi], b1[ni], acc10[mi][ni], 0, 0, 0);
                    acc11[mi][ni] = __builtin_amdgcn_mfma_f32_16x16x32_bf16(a[mi], b2[ni], acc11[mi][ni], 0, 0, 0);
                }
        }
        __syncthreads();
    }
    // half 2: k in [512,1024): A0=pa->acc00, A1=na1->acc10, A2=pb1->acc11
    for (int kq = 0; kq < 8; ++kq) {
        int cb = kq * 64;
        stage_tile<64>(pab + (size_t)m0 * 512 + cb, 512, lsA0, t);
        stage_tile<64>(na1b + (size_t)m0 * 512 + cb, 512, lsA1, t);
        stage_tile<64>(pb1b + (size_t)m0 * 512 + cb, 512, lsA2, t);
        stage_tile<128>(w00 + (size_t)n0 * 1536 + 512 + cb, 1536, lsB0, t);
        stage_tile<128>(w10 + (size_t)n0 * 1024 + 512 + cb, 1024, lsB1, t);
        stage_tile<128>(w11 + (size_t)n0 * 1024 + 512 + cb, 1024, lsB2, t);
        __syncthreads();
#pragma unroll
        for (int kk = 0; kk < 2; ++kk) {
            bf16x8 a0[2], a1[2], a2[2], b0[4], b1[4], b2[4];
#pragma unroll
            for (int mi = 0; mi < 2; ++mi) {
                a0[mi] = *(const bf16x8*)&lsA0[(wr + mi * 16 + fr) * 64 + kk * 32 + lofs];
                a1[mi] = *(const bf16x8*)&lsA1[(wr + mi * 16 + fr) * 64 + kk * 32 + lofs];
                a2[mi] = *(const bf16x8*)&lsA2[(wr + mi * 16 + fr) * 64 + kk * 32 + lofs];
            }
#pragma unroll
            for (int ni = 0; ni < 4; ++ni) {
                b0[ni] = *(const bf16x8*)&lsB0[(wc + ni * 16 + fr) * 64 + kk * 32 + lofs];
                b1[ni] = *(const bf16x8*)&lsB1[(wc + ni * 16 + fr) * 64 + kk * 32 + lofs];
                b2[ni] = *(const bf16x8*)&lsB2[(wc + ni * 16 + fr) * 64 + kk * 32 + lofs];
            }
#pragma unroll
            for (int mi = 0; mi < 2; ++mi)
#pragma unroll
                for (int ni = 0; ni < 4; ++ni) {
                    acc00[mi][ni] = __builtin_amdgcn_mfma_f32_16x16x32_bf16(a0[mi], b0[ni], acc00[mi][ni], 0, 0, 0);
                    acc10[mi][ni] = __builtin_amdgcn_mfma_f32_16x16x32_bf16(a1[mi], b1[ni], acc10[mi][ni], 0, 0, 0);
                    acc11[mi][ni] = __builtin_amdgcn_mfma_f32_16x16x32_bf16(a2[mi], b2[ni], acc11[mi][ni], 0, 0, 0);
                }
        }
        __syncthreads();
    }
    // half 3: k in [1024,1536): A = na1 -> acc00 only
    for (int kq = 0; kq < 8; ++kq) {
        int cb = kq * 64;
        stage_tile<64>(na1b + (size_t)m0 * 512 + cb, 512, lsA0, t);
        stage_tile<128>(w00 + (size_t)n0 * 1536 + 1024 + cb, 1536, lsB0, t);
        __syncthreads();
#pragma unroll
        for (int kk = 0; kk < 2; ++kk) {
            bf16x8 a[2], b0[4];
#pragma unroll
            for (int mi = 0; mi < 2; ++mi)
                a[mi] = *(const bf16x8*)&lsA0[(wr + mi * 16 + fr) * 64 + kk * 32 + lofs];
#pragma unroll
            for (int ni = 0; ni < 4; ++ni)
                b0[ni] = *(const bf16x8*)&lsB0[(wc + ni * 16 + fr) * 64 + kk * 32 + lofs];
#pragma unroll
            for (int mi = 0; mi < 2; ++mi)
#pragma unroll
                for (int ni = 0; ni < 4; ++ni)
                    acc00[mi][ni] = __builtin_amdgcn_mfma_f32_16x16x32_bf16(a[mi], b0[ni], acc00[mi][ni], 0, 0, 0);
        }
        __syncthreads();
    }
    // fused epilogue B
#pragma unroll
    for (int mi = 0; mi < 2; ++mi)
#pragma unroll
        for (int jj = 0; jj < 4; ++jj) {
            int row = m0 + wr + mi * 16 + fq * 4 + jj;
            f32x4 c = *(const f32x4*)(coeffs + (size_t)row * 4);
#pragma unroll
            for (int ni = 0; ni < 4; ++ni) {
                int col = n0 + wc + ni * 16 + fr;
                float pb1 = prev_b[(size_t)row * 1024 + 512 + col];
                float v = c.x * acc11[mi][ni][jj] + c.y * acc00[mi][ni][jj]
                        + c.z * acc10[mi][ni][jj] + c.w * pb1;
                outB[(size_t)row * 1024 + 512 + col] = v;
            }
        }
}

extern "C" void kernel_launch(void* const* d_in, const int* in_sizes, int n_in,
                              void* d_out, int out_size, void* d_ws, size_t ws_size,
                              hipStream_t stream) {
    const float* X          = (const float*)d_in[0];
    const float* prev_a     = (const float*)d_in[1];
    const float* prev_b     = (const float*)d_in[2];
    const int*   prev_depth = (const int*)d_in[3];
    const float* w_f        = (const float*)d_in[4];
    const float* w_a00      = (const float*)d_in[5];
    const float* w_a10      = (const float*)d_in[6];
    const float* w_b00      = (const float*)d_in[7];
    const float* w_b11      = (const float*)d_in[8];
    const float* w_b10      = (const float*)d_in[9];

    float* out  = (float*)d_out;
    float* outA = out;
    float* outB = out + 8388608;
    float* outD = out + 16777216;
    float* outF = outD + 8192;
    float* outJ = outF + 8192;

    char* ws = (char*)d_ws;
    size_t off = 0;
    auto alloc = [&](size_t bytes) -> char* {
        char* p = ws + off;
        off += (bytes + 255) & ~(size_t)255;
        return p;
    };
    u16* Xb    = (u16*)alloc((size_t)B_DIM * 512 * 2);
    u16* pab   = (u16*)alloc((size_t)B_DIM * 512 * 2);
    u16* pb0b  = (u16*)alloc((size_t)B_DIM * 512 * 2);
    u16* pb1b  = (u16*)alloc((size_t)B_DIM * 512 * 2);
    u16* na1b  = (u16*)alloc((size_t)B_DIM * 512 * 2);
    u16* wa00b = (u16*)alloc((size_t)512 * 1024 * 2);
    u16* wa10b = (u16*)alloc((size_t)512 * 1024 * 2);
    u16* wb00b = (u16*)alloc((size_t)512 * 1536 * 2);
    u16* wb11b = (u16*)alloc((size_t)512 * 1024 * 2);
    u16* wb10b = (u16*)alloc((size_t)512 * 1024 * 2);
    float* coeffs = (float*)alloc((size_t)B_DIM * 16);
    int* flag = (int*)alloc(256);
    if (off > ws_size) return;

    k_flag<<<1, 1024, 0, stream>>>(prev_depth, flag);
    k_prep2<<<2048, 256, 0, stream>>>(X, prev_a, prev_b, prev_depth, w_f, flag,
                                      Xb, pab, pb0b, pb1b, coeffs, outA, outB,
                                      outD, outF, outJ);
    k_conv_w<<<2816, 256, 0, stream>>>(w_a00, w_a10, w_b00, w_b11, w_b10,
                                       wa00b, wa10b, wb00b, wb11b, wb10b);
    k_gemmA<<<512, 256, 0, stream>>>(Xb, pab, pb0b, wa00b, wa10b,
                                     prev_a, coeffs, outA, na1b);
    k_gemmB<<<512, 256, 0, stream>>>(Xb, pab, na1b, pb1b, wb00b, wb10b, wb11b,
                                     prev_b, coeffs, outB);
}

// Round 3
// 97.195 us; speedup vs baseline: 2.0321x; 1.2654x over previous
//
#include <hip/hip_runtime.h>
#include <hip/hip_bf16.h>

typedef __attribute__((ext_vector_type(8))) __bf16 bf16x8;
typedef __attribute__((ext_vector_type(4))) float f32x4;
typedef __attribute__((ext_vector_type(4))) unsigned short u16x4;
typedef unsigned short u16;

typedef __attribute__((address_space(1))) void gvoid;
typedef __attribute__((address_space(3))) void lvoid;

#define B_DIM 8192
#define H_DIM 512

__device__ __forceinline__ u16x4 cvt4(f32x4 v) {
    u16x4 r;
    r.x = __builtin_bit_cast(u16, __float2bfloat16(v.x));
    r.y = __builtin_bit_cast(u16, __float2bfloat16(v.y));
    r.z = __builtin_bit_cast(u16, __float2bfloat16(v.z));
    r.w = __builtin_bit_cast(u16, __float2bfloat16(v.w));
    return r;
}

// Stage an R x 64 bf16 tile into LDS with st-style XOR swizzle.
// LDS destination is LINEAR (global_load_lds requirement); the global SOURCE
// column is pre-permuted so that LDS slot s of row r holds global slot s^(r&7).
// Readers must apply the same XOR (ld_frag below).  [rule #21: both-sides]
template<int R>
__device__ __forceinline__ void stage_tile(const u16* g, int ldg, u16* ls, int t) {
#pragma unroll
    for (int it = 0; it < R / 32; ++it) {
        int e = it * 2048 + t * 8;       // linear element in LDS tile
        int r = e >> 6;                  // row
        int slot = (e & 63) >> 3;        // 16B slot within row (0..7)
        int csrc = (slot ^ (r & 7)) << 3;
        __builtin_amdgcn_global_load_lds((gvoid*)(g + (size_t)r * ldg + csrc),
                                         (lvoid*)&ls[e], 16, 0, 0);
    }
}

// Swizzled fragment read: logical (row, kslot) -> physical slot kslot^(row&7).
// 16 fr-lanes hit 8 distinct 16B slots (2-way, free) instead of 16-way same-bank.
__device__ __forceinline__ bf16x8 ld_frag(const u16* ls, int row, int kslot) {
    return *(const bf16x8*)&ls[row * 64 + ((kslot ^ (row & 7)) << 3)];
}

// ---------------- all_zero flag ----------------
__global__ void k_flag(const int* __restrict__ pd, int* __restrict__ flag) {
    __shared__ int s;
    if (threadIdx.x == 0) s = 0;
    __syncthreads();
    int any = 0;
    for (int i = threadIdx.x; i < B_DIM; i += 1024) any |= pd[i];
    if (any) atomicOr(&s, 1);
    __syncthreads();
    if (threadIdx.x == 0) flag[0] = (s == 0) ? 1 : 0;
}

// ---------------- fused prep: f/j/depth/coeffs + bf16 conversion + zero slabs ----------------
__global__ void k_prep2(const float* __restrict__ X, const float* __restrict__ prev_a,
                        const float* __restrict__ prev_b, const int* __restrict__ prev_depth,
                        const float* __restrict__ w_f, const int* __restrict__ flag,
                        u16* __restrict__ Xb, u16* __restrict__ pab,
                        u16* __restrict__ pb0b, u16* __restrict__ pb1b,
                        float* __restrict__ coeffs, float* __restrict__ outA,
                        float* __restrict__ outB, float* __restrict__ outD,
                        float* __restrict__ outF, float* __restrict__ outJ) {
    int wv = threadIdx.x >> 6, l = threadIdx.x & 63;
    int row = blockIdx.x * 4 + wv;
    size_t r512 = (size_t)row * 512, r1024 = (size_t)row * 1024;
    int i = l * 8;
    f32x4 x0  = *(const f32x4*)(X + r512 + i);
    f32x4 x1  = *(const f32x4*)(X + r512 + i + 4);
    f32x4 pa0 = *(const f32x4*)(prev_a + r1024 + 512 + i);
    f32x4 pa1 = *(const f32x4*)(prev_a + r1024 + 512 + i + 4);
    f32x4 q00 = *(const f32x4*)(prev_b + r1024 + i);
    f32x4 q01 = *(const f32x4*)(prev_b + r1024 + i + 4);
    f32x4 q10 = *(const f32x4*)(prev_b + r1024 + 512 + i);
    f32x4 q11 = *(const f32x4*)(prev_b + r1024 + 512 + i + 4);
    f32x4 w0  = *(const f32x4*)(w_f + i);
    f32x4 w1  = *(const f32x4*)(w_f + i + 4);
    int depth = prev_depth[row];
    f32x4 b0 = depth ? q10 : q00;
    f32x4 b1 = depth ? q11 : q01;
    float dot = b0.x*w0.x + b0.y*w0.y + b0.z*w0.z + b0.w*w0.w
              + b1.x*w1.x + b1.y*w1.y + b1.z*w1.z + b1.w*w1.w;
    for (int off = 32; off > 0; off >>= 1) dot += __shfl_xor(dot, off, 64);

    *(u16x4*)(Xb   + r512 + i)     = cvt4(x0);
    *(u16x4*)(Xb   + r512 + i + 4) = cvt4(x1);
    *(u16x4*)(pab  + r512 + i)     = cvt4(pa0);
    *(u16x4*)(pab  + r512 + i + 4) = cvt4(pa1);
    *(u16x4*)(pb0b + r512 + i)     = cvt4(q00);
    *(u16x4*)(pb0b + r512 + i + 4) = cvt4(q01);
    *(u16x4*)(pb1b + r512 + i)     = cvt4(q10);
    *(u16x4*)(pb1b + r512 + i + 4) = cvt4(q11);
    f32x4 z; z.x = 0.f; z.y = 0.f; z.z = 0.f; z.w = 0.f;
    *(f32x4*)(outA + r1024 + i)     = z;
    *(f32x4*)(outA + r1024 + i + 4) = z;
    *(f32x4*)(outB + r1024 + i)     = z;
    *(f32x4*)(outB + r1024 + i + 4) = z;

    if (l == 0) {
        int az = flag[0];
        float sg = 1.0f / (1.0f + expf(-dot));
        float fr = rintf(sg);
        float f = az ? 1.0f : fr;
        float j = az ? 0.0f : fr;
        int nd = depth + (int)(f - j);
        float eq = (nd == 1) ? 1.0f : 0.0f;
        float lt = (nd < 1) ? 1.0f : 0.0f;
        f32x4 c; c.x = eq * (f * j); c.y = eq * (1.0f - f) * (1.0f - j);
        c.z = eq * f * (1.0f - j); c.w = lt;
        *(f32x4*)(coeffs + (size_t)row * 4) = c;
        outD[row] = (float)nd;
        outF[row] = f;
        outJ[row] = j;
    }
}

// ---------------- convert all 5 weight matrices to bf16 ----------------
__global__ void k_conv_w(const float* __restrict__ wa00, const float* __restrict__ wa10,
                         const float* __restrict__ wb00, const float* __restrict__ wb11,
                         const float* __restrict__ wb10,
                         u16* __restrict__ oa00, u16* __restrict__ oa10,
                         u16* __restrict__ ob00, u16* __restrict__ ob11,
                         u16* __restrict__ ob10) {
    int t = blockIdx.x * 256 + threadIdx.x;
    const int S  = 512 * 1024 / 4;
    const int SB = 512 * 1536 / 4;
    const float* src; u16* dst; int off;
    if      (t < S)            { src = wa00; dst = oa00; off = t; }
    else if (t < 2 * S)        { src = wa10; dst = oa10; off = t - S; }
    else if (t < 2 * S + SB)   { src = wb00; dst = ob00; off = t - 2 * S; }
    else if (t < 3 * S + SB)   { src = wb11; dst = ob11; off = t - 2 * S - SB; }
    else if (t < 4 * S + SB)   { src = wb10; dst = ob10; off = t - 3 * S - SB; }
    else return;
    f32x4 v = *(const f32x4*)(src + (size_t)off * 4);
    *(u16x4*)(dst + (size_t)off * 4) = cvt4(v);
}

// ---------------- phase-1 fused GEMM: a00 & a10 + epilogue A ----------------
// 512 blocks (64-row M-tile x 128-col N-tile), 256 threads, 2 blocks/CU.
__global__ __launch_bounds__(256, 2) void k_gemmA(
    const u16* __restrict__ Xb, const u16* __restrict__ pab, const u16* __restrict__ pb0b,
    const u16* __restrict__ w0, const u16* __restrict__ w1,
    const float* __restrict__ prev_a, const float* __restrict__ coeffs,
    float* __restrict__ outA, u16* __restrict__ na1b)
{
    __shared__ u16 lsA0[64 * 64];
    __shared__ u16 lsA1[64 * 64];
    __shared__ u16 lsB0[128 * 64];
    __shared__ u16 lsB1[128 * 64];
    const int t = threadIdx.x;
    // XCD-aware swizzle: 512 blocks, 8 XCDs -> each XCD gets a contiguous
    // M-major chunk of 64; the 4 N-blocks of one M-tile share one L2.
    int bid = ((int)blockIdx.x & 7) * 64 + ((int)blockIdx.x >> 3);
    const int m0 = (bid >> 2) * 64;
    const int n0 = (bid & 3) * 128;
    const int lane = t & 63, wv = t >> 6;
    const int wr = (wv >> 1) * 32, wc = (wv & 1) * 64;
    const int fr = lane & 15, fq = lane >> 4;

    f32x4 acc0[2][4] = {}, acc1[2][4] = {};

    // half 1: k in [0,512), A = X for both outputs
    for (int kq = 0; kq < 8; ++kq) {
        int cb = kq * 64;
        stage_tile<64>(Xb + (size_t)m0 * 512 + cb, 512, lsA0, t);
        stage_tile<128>(w0 + (size_t)n0 * 1024 + cb, 1024, lsB0, t);
        stage_tile<128>(w1 + (size_t)n0 * 1024 + cb, 1024, lsB1, t);
        __syncthreads();
#pragma unroll
        for (int kk = 0; kk < 2; ++kk) {
            int ks = kk * 4 + fq;
            bf16x8 a[2], b0[4], b1[4];
#pragma unroll
            for (int mi = 0; mi < 2; ++mi)
                a[mi] = ld_frag(lsA0, wr + mi * 16 + fr, ks);
#pragma unroll
            for (int ni = 0; ni < 4; ++ni) {
                b0[ni] = ld_frag(lsB0, wc + ni * 16 + fr, ks);
                b1[ni] = ld_frag(lsB1, wc + ni * 16 + fr, ks);
            }
#pragma unroll
            for (int mi = 0; mi < 2; ++mi)
#pragma unroll
                for (int ni = 0; ni < 4; ++ni) {
                    acc0[mi][ni] = __builtin_amdgcn_mfma_f32_16x16x32_bf16(a[mi], b0[ni], acc0[mi][ni], 0, 0, 0);
                    acc1[mi][ni] = __builtin_amdgcn_mfma_f32_16x16x32_bf16(a[mi], b1[ni], acc1[mi][ni], 0, 0, 0);
                }
        }
        __syncthreads();
    }
    // half 2: k in [512,1024), A0 = pa (acc0), A1 = pb0 (acc1)
    for (int kq = 0; kq < 8; ++kq) {
        int cb = kq * 64;
        stage_tile<64>(pab + (size_t)m0 * 512 + cb, 512, lsA0, t);
        stage_tile<64>(pb0b + (size_t)m0 * 512 + cb, 512, lsA1, t);
        stage_tile<128>(w0 + (size_t)n0 * 1024 + 512 + cb, 1024, lsB0, t);
        stage_tile<128>(w1 + (size_t)n0 * 1024 + 512 + cb, 1024, lsB1, t);
        __syncthreads();
#pragma unroll
        for (int kk = 0; kk < 2; ++kk) {
            int ks = kk * 4 + fq;
            bf16x8 a0[2], a1[2], b0[4], b1[4];
#pragma unroll
            for (int mi = 0; mi < 2; ++mi) {
                a0[mi] = ld_frag(lsA0, wr + mi * 16 + fr, ks);
                a1[mi] = ld_frag(lsA1, wr + mi * 16 + fr, ks);
            }
#pragma unroll
            for (int ni = 0; ni < 4; ++ni) {
                b0[ni] = ld_frag(lsB0, wc + ni * 16 + fr, ks);
                b1[ni] = ld_frag(lsB1, wc + ni * 16 + fr, ks);
            }
#pragma unroll
            for (int mi = 0; mi < 2; ++mi)
#pragma unroll
                for (int ni = 0; ni < 4; ++ni) {
                    acc0[mi][ni] = __builtin_amdgcn_mfma_f32_16x16x32_bf16(a0[mi], b0[ni], acc0[mi][ni], 0, 0, 0);
                    acc1[mi][ni] = __builtin_amdgcn_mfma_f32_16x16x32_bf16(a1[mi], b1[ni], acc1[mi][ni], 0, 0, 0);
                }
        }
        __syncthreads();
    }
    // fused epilogue A
#pragma unroll
    for (int mi = 0; mi < 2; ++mi)
#pragma unroll
        for (int jj = 0; jj < 4; ++jj) {
            int row = m0 + wr + mi * 16 + fq * 4 + jj;
            f32x4 c = *(const f32x4*)(coeffs + (size_t)row * 4);
            float cpa = c.x + c.w;
#pragma unroll
            for (int ni = 0; ni < 4; ++ni) {
                int col = n0 + wc + ni * 16 + fr;
                float pa = prev_a[(size_t)row * 1024 + 512 + col];
                float v = cpa * pa + c.y * acc0[mi][ni][jj] + c.z * acc1[mi][ni][jj];
                outA[(size_t)row * 1024 + 512 + col] = v;
                na1b[(size_t)row * 512 + col] = __builtin_bit_cast(u16, __float2bfloat16(v));
            }
        }
}

// ---------------- phase-2 fused GEMM: b00, b10, b11 + epilogue B ----------------
__global__ __launch_bounds__(256, 2) void k_gemmB(
    const u16* __restrict__ Xb, const u16* __restrict__ pab,
    const u16* __restrict__ na1b, const u16* __restrict__ pb1b,
    const u16* __restrict__ w00, const u16* __restrict__ w10, const u16* __restrict__ w11,
    const float* __restrict__ prev_b, const float* __restrict__ coeffs,
    float* __restrict__ outB)
{
    __shared__ u16 lsA0[64 * 64];
    __shared__ u16 lsA1[64 * 64];
    __shared__ u16 lsA2[64 * 64];
    __shared__ u16 lsB0[128 * 64];
    __shared__ u16 lsB1[128 * 64];
    __shared__ u16 lsB2[128 * 64];
    const int t = threadIdx.x;
    int bid = ((int)blockIdx.x & 7) * 64 + ((int)blockIdx.x >> 3);
    const int m0 = (bid >> 2) * 64;
    const int n0 = (bid & 3) * 128;
    const int lane = t & 63, wv = t >> 6;
    const int wr = (wv >> 1) * 32, wc = (wv & 1) * 64;
    const int fr = lane & 15, fq = lane >> 4;

    f32x4 acc00[2][4] = {}, acc10[2][4] = {}, acc11[2][4] = {};

    // half 1: k in [0,512), A = X for all three
    for (int kq = 0; kq < 8; ++kq) {
        int cb = kq * 64;
        stage_tile<64>(Xb + (size_t)m0 * 512 + cb, 512, lsA0, t);
        stage_tile<128>(w00 + (size_t)n0 * 1536 + cb, 1536, lsB0, t);
        stage_tile<128>(w10 + (size_t)n0 * 1024 + cb, 1024, lsB1, t);
        stage_tile<128>(w11 + (size_t)n0 * 1024 + cb, 1024, lsB2, t);
        __syncthreads();
#pragma unroll
        for (int kk = 0; kk < 2; ++kk) {
            int ks = kk * 4 + fq;
            bf16x8 a[2], b0[4], b1[4], b2[4];
#pragma unroll
            for (int mi = 0; mi < 2; ++mi)
                a[mi] = ld_frag(lsA0, wr + mi * 16 + fr, ks);
#pragma unroll
            for (int ni = 0; ni < 4; ++ni) {
                b0[ni] = ld_frag(lsB0, wc + ni * 16 + fr, ks);
                b1[ni] = ld_frag(lsB1, wc + ni * 16 + fr, ks);
                b2[ni] = ld_frag(lsB2, wc + ni * 16 + fr, ks);
            }
#pragma unroll
            for (int mi = 0; mi < 2; ++mi)
#pragma unroll
                for (int ni = 0; ni < 4; ++ni) {
                    acc00[mi][ni] = __builtin_amdgcn_mfma_f32_16x16x32_bf16(a[mi], b0[ni], acc00[mi][ni], 0, 0, 0);
                    acc10[mi][ni] = __builtin_amdgcn_mfma_f32_16x16x32_bf16(a[mi], b1[ni], acc10[mi][ni], 0, 0, 0);
                    acc11[mi][ni] = __builtin_amdgcn_mfma_f32_16x16x32_bf16(a[mi], b2[ni], acc11[mi][ni], 0, 0, 0);
                }
        }
        __syncthreads();
    }
    // half 2: k in [512,1024): A0=pa->acc00, A1=na1->acc10, A2=pb1->acc11
    for (int kq = 0; kq < 8; ++kq) {
        int cb = kq * 64;
        stage_tile<64>(pab + (size_t)m0 * 512 + cb, 512, lsA0, t);
        stage_tile<64>(na1b + (size_t)m0 * 512 + cb, 512, lsA1, t);
        stage_tile<64>(pb1b + (size_t)m0 * 512 + cb, 512, lsA2, t);
        stage_tile<128>(w00 + (size_t)n0 * 1536 + 512 + cb, 1536, lsB0, t);
        stage_tile<128>(w10 + (size_t)n0 * 1024 + 512 + cb, 1024, lsB1, t);
        stage_tile<128>(w11 + (size_t)n0 * 1024 + 512 + cb, 1024, lsB2, t);
        __syncthreads();
#pragma unroll
        for (int kk = 0; kk < 2; ++kk) {
            int ks = kk * 4 + fq;
            bf16x8 a0[2], a1[2], a2[2], b0[4], b1[4], b2[4];
#pragma unroll
            for (int mi = 0; mi < 2; ++mi) {
                a0[mi] = ld_frag(lsA0, wr + mi * 16 + fr, ks);
                a1[mi] = ld_frag(lsA1, wr + mi * 16 + fr, ks);
                a2[mi] = ld_frag(lsA2, wr + mi * 16 + fr, ks);
            }
#pragma unroll
            for (int ni = 0; ni < 4; ++ni) {
                b0[ni] = ld_frag(lsB0, wc + ni * 16 + fr, ks);
                b1[ni] = ld_frag(lsB1, wc + ni * 16 + fr, ks);
                b2[ni] = ld_frag(lsB2, wc + ni * 16 + fr, ks);
            }
#pragma unroll
            for (int mi = 0; mi < 2; ++mi)
#pragma unroll
                for (int ni = 0; ni < 4; ++ni) {
                    acc00[mi][ni] = __builtin_amdgcn_mfma_f32_16x16x32_bf16(a0[mi], b0[ni], acc00[mi][ni], 0, 0, 0);
                    acc10[mi][ni] = __builtin_amdgcn_mfma_f32_16x16x32_bf16(a1[mi], b1[ni], acc10[mi][ni], 0, 0, 0);
                    acc11[mi][ni] = __builtin_amdgcn_mfma_f32_16x16x32_bf16(a2[mi], b2[ni], acc11[mi][ni], 0, 0, 0);
                }
        }
        __syncthreads();
    }
    // half 3: k in [1024,1536): A = na1 -> acc00 only
    for (int kq = 0; kq < 8; ++kq) {
        int cb = kq * 64;
        stage_tile<64>(na1b + (size_t)m0 * 512 + cb, 512, lsA0, t);
        stage_tile<128>(w00 + (size_t)n0 * 1536 + 1024 + cb, 1536, lsB0, t);
        __syncthreads();
#pragma unroll
        for (int kk = 0; kk < 2; ++kk) {
            int ks = kk * 4 + fq;
            bf16x8 a[2], b0[4];
#pragma unroll
            for (int mi = 0; mi < 2; ++mi)
                a[mi] = ld_frag(lsA0, wr + mi * 16 + fr, ks);
#pragma unroll
            for (int ni = 0; ni < 4; ++ni)
                b0[ni] = ld_frag(lsB0, wc + ni * 16 + fr, ks);
#pragma unroll
            for (int mi = 0; mi < 2; ++mi)
#pragma unroll
                for (int ni = 0; ni < 4; ++ni)
                    acc00[mi][ni] = __builtin_amdgcn_mfma_f32_16x16x32_bf16(a[mi], b0[ni], acc00[mi][ni], 0, 0, 0);
        }
        __syncthreads();
    }
    // fused epilogue B
#pragma unroll
    for (int mi = 0; mi < 2; ++mi)
#pragma unroll
        for (int jj = 0; jj < 4; ++jj) {
            int row = m0 + wr + mi * 16 + fq * 4 + jj;
            f32x4 c = *(const f32x4*)(coeffs + (size_t)row * 4);
#pragma unroll
            for (int ni = 0; ni < 4; ++ni) {
                int col = n0 + wc + ni * 16 + fr;
                float pb1 = prev_b[(size_t)row * 1024 + 512 + col];
                float v = c.x * acc11[mi][ni][jj] + c.y * acc00[mi][ni][jj]
                        + c.z * acc10[mi][ni][jj] + c.w * pb1;
                outB[(size_t)row * 1024 + 512 + col] = v;
            }
        }
}

extern "C" void kernel_launch(void* const* d_in, const int* in_sizes, int n_in,
                              void* d_out, int out_size, void* d_ws, size_t ws_size,
                              hipStream_t stream) {
    const float* X          = (const float*)d_in[0];
    const float* prev_a     = (const float*)d_in[1];
    const float* prev_b     = (const float*)d_in[2];
    const int*   prev_depth = (const int*)d_in[3];
    const float* w_f        = (const float*)d_in[4];
    const float* w_a00      = (const float*)d_in[5];
    const float* w_a10      = (const float*)d_in[6];
    const float* w_b00      = (const float*)d_in[7];
    const float* w_b11      = (const float*)d_in[8];
    const float* w_b10      = (const float*)d_in[9];

    float* out  = (float*)d_out;
    float* outA = out;
    float* outB = out + 8388608;
    float* outD = out + 16777216;
    float* outF = outD + 8192;
    float* outJ = outF + 8192;

    char* ws = (char*)d_ws;
    size_t off = 0;
    auto alloc = [&](size_t bytes) -> char* {
        char* p = ws + off;
        off += (bytes + 255) & ~(size_t)255;
        return p;
    };
    u16* Xb    = (u16*)alloc((size_t)B_DIM * 512 * 2);
    u16* pab   = (u16*)alloc((size_t)B_DIM * 512 * 2);
    u16* pb0b  = (u16*)alloc((size_t)B_DIM * 512 * 2);
    u16* pb1b  = (u16*)alloc((size_t)B_DIM * 512 * 2);
    u16* na1b  = (u16*)alloc((size_t)B_DIM * 512 * 2);
    u16* wa00b = (u16*)alloc((size_t)512 * 1024 * 2);
    u16* wa10b = (u16*)alloc((size_t)512 * 1024 * 2);
    u16* wb00b = (u16*)alloc((size_t)512 * 1536 * 2);
    u16* wb11b = (u16*)alloc((size_t)512 * 1024 * 2);
    u16* wb10b = (u16*)alloc((size_t)512 * 1024 * 2);
    float* coeffs = (float*)alloc((size_t)B_DIM * 16);
    int* flag = (int*)alloc(256);
    if (off > ws_size) return;

    k_flag<<<1, 1024, 0, stream>>>(prev_depth, flag);
    k_prep2<<<2048, 256, 0, stream>>>(X, prev_a, prev_b, prev_depth, w_f, flag,
                                      Xb, pab, pb0b, pb1b, coeffs, outA, outB,
                                      outD, outF, outJ);
    k_conv_w<<<2816, 256, 0, stream>>>(w_a00, w_a10, w_b00, w_b11, w_b10,
                                       wa00b, wa10b, wb00b, wb11b, wb10b);
    k_gemmA<<<512, 256, 0, stream>>>(Xb, pab, pb0b, wa00b, wa10b,
                                     prev_a, coeffs, outA, na1b);
    k_gemmB<<<512, 256, 0, stream>>>(Xb, pab, na1b, pb1b, wb00b, wb10b, wb11b,
                                     prev_b, coeffs, outB);
}